// Round 1
// baseline (898.591 us; speedup 1.0000x reference)
//
#include <hip/hip_runtime.h>
#include <hip/hip_bf16.h>

// Problem constants
#define HW_   784          // 28*28 locations
#define C_IN  256
#define BS    64
#define OC_   64
#define D_TOT 1024         // OC*4*4
#define OH_   31
#define OW_   31

typedef __attribute__((ext_vector_type(8))) short  short8;   // 8 bf16 (4 VGPR) MFMA A/B frag
typedef __attribute__((ext_vector_type(4))) float  f32x4;    // MFMA C/D frag
typedef __attribute__((ext_vector_type(4))) int    int4v;

static __device__ __forceinline__ short f2bf(float f) {
    // round-to-nearest-even fp32 -> bf16
    unsigned int u = __float_as_uint(f);
    unsigned int r = (u + 0x7fffu + ((u >> 16) & 1u)) >> 16;
    return (short)r;
}

// ---------------------------------------------------------------------------
// Kernel 0: pack x[b, c, l] (fp32, l contiguous) -> xp[l][b][c] (bf16, c contiguous)
// Tiling: block = (b, c-block of 32, l-block of 112). 64 x 8 x 7 = 3584 blocks.
// Reads coalesced along l; writes coalesced along c.
// ---------------------------------------------------------------------------
__global__ __launch_bounds__(256) void pack_x(const float* __restrict__ x,
                                              __hip_bfloat16* __restrict__ xp) {
    const int b  = blockIdx.x;
    const int c0 = blockIdx.y * 32;
    const int l0 = blockIdx.z * 112;
    const int t  = threadIdx.x;

    __shared__ unsigned short tile[32][114];   // +2 pad -> conflict-free transpose reads

    // load: 32 c-rows x 112 l (coalesced along l)
    for (int e = t; e < 32 * 112; e += 256) {
        int cl = e / 112, ll = e % 112;
        float v = x[(size_t)b * (C_IN * HW_) + (size_t)(c0 + cl) * HW_ + (l0 + ll)];
        tile[cl][ll] = (unsigned short)f2bf(v);
    }
    __syncthreads();

    // store: per l, 32 consecutive c bf16 (coalesced along c)
    for (int e = t; e < 112 * 32; e += 256) {
        int ll = e >> 5, cl = e & 31;
        xp[(size_t)(l0 + ll) * (BS * C_IN) + b * C_IN + (c0 + cl)] =
            *(const __hip_bfloat16*)&tile[cl][ll];
    }
}

// ---------------------------------------------------------------------------
// Kernel 1: per (location l, 256-wide d-chunk) GEMM  [64b x 256c] @ [256c x 256d]
// + scatter overlap-add into out via fp32 HW atomics.
// Block: 256 threads = 4 waves; wave w owns d-range [chunk*256 + w*64, +64).
// A (x) staged in LDS (XOR-swizzled rows); B (weight) streamed global->reg,
// converted to bf16 in-register (weight has zero reuse -> no LDS).
// ---------------------------------------------------------------------------
__global__ __launch_bounds__(256) void lc_gemm(const __hip_bfloat16* __restrict__ xp,
                                               const float* __restrict__ W,
                                               float* __restrict__ out) {
    const int l     = blockIdx.x >> 2;
    const int chunk = blockIdx.x & 3;
    const int t     = threadIdx.x;
    const int wave  = t >> 6;
    const int lane  = t & 63;
    const int g     = lane >> 4;      // 0..3  (k-group)
    const int ln    = lane & 15;      // row/col within fragment

    __shared__ int4v alds4[2048];     // 32 KB: A tile 64 rows(b) x 256 c bf16, row = 512 B
    char* alds = (char*)alds4;

    // ---- stage A tile (coalesced 16B loads; XOR swizzle byte ^= (row&7)<<4) ----
    {
        const int4v* src = (const int4v*)(xp + (size_t)l * (BS * C_IN));
        #pragma unroll
        for (int it = 0; it < 8; ++it) {
            int ch  = t + it * 256;        // 16B granule id, 0..2047
            int row = ch >> 5;             // b row (512B per row)
            int col = ch & 31;             // 16B granule within row
            int4v v = src[ch];
            *(int4v*)(alds + row * 512 + ((col * 16) ^ ((row & 7) << 4))) = v;
        }
    }
    __syncthreads();

    const float* Wl    = W + (size_t)l * (C_IN * D_TOT);
    const int    dbase = chunk * 256 + wave * 64;

    f32x4 acc[4][4];
    #pragma unroll
    for (int m = 0; m < 4; ++m)
        #pragma unroll
        for (int n = 0; n < 4; ++n)
            acc[m][n] = (f32x4){0.f, 0.f, 0.f, 0.f};

    for (int k0 = 0; k0 < C_IN; k0 += 32) {
        // B fragments: lane holds W[k0 + g*8 + tt][dbase + 16n + ln], tt=0..7
        float wv[4][8];
        #pragma unroll
        for (int n = 0; n < 4; ++n) {
            const float* p = Wl + (size_t)(k0 + g * 8) * D_TOT + (dbase + 16 * n + ln);
            #pragma unroll
            for (int tt = 0; tt < 8; ++tt) wv[n][tt] = p[(size_t)tt * D_TOT];
        }

        // A fragments from LDS: lane holds x[b = 16m + ln][k0 + g*8 .. +7]
        short8 af[4];
        #pragma unroll
        for (int m = 0; m < 4; ++m) {
            int row = 16 * m + ln;
            int off = row * 512 + ((((k0 + g * 8) << 1)) ^ ((row & 7) << 4));
            af[m] = *(const short8*)(alds + off);
        }

        short8 bf[4];
        #pragma unroll
        for (int n = 0; n < 4; ++n)
            #pragma unroll
            for (int tt = 0; tt < 8; ++tt) bf[n][tt] = f2bf(wv[n][tt]);

        #pragma unroll
        for (int m = 0; m < 4; ++m)
            #pragma unroll
            for (int n = 0; n < 4; ++n)
                acc[m][n] = __builtin_amdgcn_mfma_f32_16x16x32_bf16(af[m], bf[n],
                                                                   acc[m][n], 0, 0, 0);
    }

    // ---- epilogue: fold scatter with fp32 HW atomics ----
    // C layout (16x16x32): col = lane&15 (d), row = (lane>>4)*4 + r (b)
    const int i = l / 28, j = l % 28;
    #pragma unroll
    for (int n = 0; n < 4; ++n) {
        int d  = dbase + 16 * n + ln;
        int oc = d >> 4;
        int q  = d & 15;
        int di = q >> 2, dj = q & 3;
        size_t obase = (size_t)oc * (OH_ * OW_) + (size_t)(i + di) * OW_ + (j + dj);
        #pragma unroll
        for (int m = 0; m < 4; ++m) {
            #pragma unroll
            for (int r = 0; r < 4; ++r) {
                int b = 16 * m + g * 4 + r;
                unsafeAtomicAdd(out + (size_t)b * (OC_ * OH_ * OW_) + obase, acc[m][n][r]);
            }
        }
    }
}

// ---------------------------------------------------------------------------
extern "C" void kernel_launch(void* const* d_in, const int* in_sizes, int n_in,
                              void* d_out, int out_size, void* d_ws, size_t ws_size,
                              hipStream_t stream) {
    const float* x = (const float*)d_in[0];
    const float* W = (const float*)d_in[1];
    float* out     = (float*)d_out;
    __hip_bfloat16* xp = (__hip_bfloat16*)d_ws;   // needs 64*256*784*2 = 25.7 MB

    // zero output (atomically accumulated below); graph-capturable
    hipMemsetAsync(d_out, 0, (size_t)out_size * sizeof(float), stream);

    pack_x<<<dim3(64, 8, 7), 256, 0, stream>>>(x, xp);
    lc_gemm<<<dim3(HW_ * 4), 256, 0, stream>>>(xp, W, out);
}

// Round 2
// 265.450 us; speedup vs baseline: 3.3852x; 3.3852x over previous
//
#include <hip/hip_runtime.h>
#include <hip/hip_bf16.h>

// Problem constants
#define HW_   784          // 28*28 locations
#define C_IN  256
#define BS    64
#define OC_   64
#define D_TOT 1024         // OC*4*4
#define OH_   31
#define OW_   31

typedef __attribute__((ext_vector_type(8))) short    short8;   // 8 bf16 (4 VGPR) MFMA A/B frag
typedef __attribute__((ext_vector_type(4))) float    f32x4;    // MFMA C/D frag
typedef __attribute__((ext_vector_type(4))) int      int4v;
typedef __attribute__((ext_vector_type(4))) _Float16 half4;

static __device__ __forceinline__ short f2bf(float f) {
    // round-to-nearest-even fp32 -> bf16
    unsigned int u = __float_as_uint(f);
    unsigned int r = (u + 0x7fffu + ((u >> 16) & 1u)) >> 16;
    return (short)r;
}

// ---------------------------------------------------------------------------
// Kernel 0: pack x[b, c, l] (fp32, l contiguous) -> xp[l][b][c] (bf16, c contiguous)
// ---------------------------------------------------------------------------
__global__ __launch_bounds__(256) void pack_x(const float* __restrict__ x,
                                              __hip_bfloat16* __restrict__ xp) {
    const int b  = blockIdx.x;
    const int c0 = blockIdx.y * 32;
    const int l0 = blockIdx.z * 112;
    const int t  = threadIdx.x;

    __shared__ unsigned short tile[32][114];   // +2 pad -> conflict-free transpose reads

    for (int e = t; e < 32 * 112; e += 256) {
        int cl = e / 112, ll = e % 112;
        float v = x[(size_t)b * (C_IN * HW_) + (size_t)(c0 + cl) * HW_ + (l0 + ll)];
        tile[cl][ll] = (unsigned short)f2bf(v);
    }
    __syncthreads();

    for (int e = t; e < 112 * 32; e += 256) {
        int ll = e >> 5, cl = e & 31;
        xp[(size_t)(l0 + ll) * (BS * C_IN) + b * C_IN + (c0 + cl)] =
            *(const __hip_bfloat16*)&tile[cl][ll];
    }
}

// ---------------------------------------------------------------------------
// Kernel 1: per (location l, 256-wide d-chunk) GEMM  [64b x 256c] @ [256c x 256d]
// Writes patches[l][b][d] (fp16) via LDS transpose -> coalesced 16B stores.
// NO atomics. XCD-swizzled grid so 4 chunks of same l share an XCD L2 (xp reuse).
// ---------------------------------------------------------------------------
__global__ __launch_bounds__(256) void lc_gemm(const __hip_bfloat16* __restrict__ xp,
                                               const float* __restrict__ W,
                                               _Float16* __restrict__ patches) {
    // XCD-aware swizzle: nwg = 3136 = 8 * 392; keep 4 chunks of one l on one XCD
    const int wg   = blockIdx.x;
    const int lcid = (wg & 7) * 392 + (wg >> 3);
    const int l     = lcid >> 2;
    const int chunk = lcid & 3;

    const int t     = threadIdx.x;
    const int wave  = t >> 6;
    const int lane  = t & 63;
    const int g     = lane >> 4;      // 0..3  (k-group)
    const int ln    = lane & 15;      // row/col within fragment

    __shared__ int4v alds4[2048];     // 32 KB: A tile 64 rows(b) x 256 c bf16, row = 512 B
    char* alds = (char*)alds4;

    // ---- stage A tile (coalesced 16B loads; XOR swizzle byte ^= (row&7)<<4) ----
    {
        const int4v* src = (const int4v*)(xp + (size_t)l * (BS * C_IN));
        #pragma unroll
        for (int it = 0; it < 8; ++it) {
            int ch  = t + it * 256;        // 16B granule id, 0..2047
            int row = ch >> 5;             // b row (512B per row)
            int col = ch & 31;             // 16B granule within row
            int4v v = src[ch];
            *(int4v*)(alds + row * 512 + ((col * 16) ^ ((row & 7) << 4))) = v;
        }
    }
    __syncthreads();

    const float* Wl    = W + (size_t)l * (C_IN * D_TOT);
    const int    dbase = chunk * 256 + wave * 64;

    f32x4 acc[4][4];
    #pragma unroll
    for (int m = 0; m < 4; ++m)
        #pragma unroll
        for (int n = 0; n < 4; ++n)
            acc[m][n] = (f32x4){0.f, 0.f, 0.f, 0.f};

    for (int k0 = 0; k0 < C_IN; k0 += 32) {
        // B fragments: lane holds W[k0 + g*8 + tt][dbase + 16n + ln], tt=0..7
        float wv[4][8];
        #pragma unroll
        for (int n = 0; n < 4; ++n) {
            const float* p = Wl + (size_t)(k0 + g * 8) * D_TOT + (dbase + 16 * n + ln);
            #pragma unroll
            for (int tt = 0; tt < 8; ++tt) wv[n][tt] = p[(size_t)tt * D_TOT];
        }

        // A fragments from LDS: lane holds x[b = 16m + ln][k0 + g*8 .. +7]
        short8 af[4];
        #pragma unroll
        for (int m = 0; m < 4; ++m) {
            int row = 16 * m + ln;
            int off = row * 512 + ((((k0 + g * 8) << 1)) ^ ((row & 7) << 4));
            af[m] = *(const short8*)(alds + off);
        }

        short8 bf[4];
        #pragma unroll
        for (int n = 0; n < 4; ++n)
            #pragma unroll
            for (int tt = 0; tt < 8; ++tt) bf[n][tt] = f2bf(wv[n][tt]);

        #pragma unroll
        for (int m = 0; m < 4; ++m)
            #pragma unroll
            for (int n = 0; n < 4; ++n)
                acc[m][n] = __builtin_amdgcn_mfma_f32_16x16x32_bf16(af[m], bf[n],
                                                                   acc[m][n], 0, 0, 0);
    }

    // ---- epilogue: LDS transpose to fp16, then coalesced global stores ----
    __syncthreads();                       // A tile no longer needed by any wave
    _Float16* hl = (_Float16*)alds;        // reuse: [64 b][256 d'] fp16 = 32 KB
    #pragma unroll
    for (int m = 0; m < 4; ++m) {
        #pragma unroll
        for (int n = 0; n < 4; ++n) {
            #pragma unroll
            for (int r = 0; r < 4; ++r) {
                int b  = 16 * m + g * 4 + r;
                int dp = wave * 64 + 16 * n + ln;   // d' within this 256-chunk
                hl[b * 256 + dp] = (_Float16)acc[m][n][r];
            }
        }
    }
    __syncthreads();

    _Float16* dst = patches + (size_t)l * (BS * D_TOT) + chunk * 256;
    #pragma unroll
    for (int it = 0; it < 8; ++it) {
        int idx = t + it * 256;            // 16B granule id, 0..2047
        int row = idx >> 5;                // b (32 granules per 512B row)
        int gg  = idx & 31;
        *(int4v*)(dst + (size_t)row * D_TOT + gg * 8) =
            *(const int4v*)(hl + row * 256 + gg * 8);
    }
}

// ---------------------------------------------------------------------------
// Kernel 2: fold (overlap-add) gather — no atomics, every patch read once.
// Block = (b, oh-group of 4). Thread = (oc = t>>2, ww = t&3) owns ow = ww*8..+7.
// d encodes di -> each 8B piece (4 dj values) contributes to exactly one oh.
// ---------------------------------------------------------------------------
__global__ __launch_bounds__(256) void fold_k(const _Float16* __restrict__ patches,
                                              float* __restrict__ out) {
    const int b   = blockIdx.x;     // 0..63
    const int oh0 = blockIdx.y * 4; // 0,4,...,28
    const int t   = threadIdx.x;
    const int oc  = t >> 2;
    const int ww  = t & 3;
    const int wb  = ww * 8;

    float acc[4][8];
    #pragma unroll
    for (int a = 0; a < 4; ++a)
        #pragma unroll
        for (int o = 0; o < 8; ++o) acc[a][o] = 0.f;

    const size_t pboc = (size_t)b * D_TOT + (size_t)oc * 16;

    #pragma unroll
    for (int a = 0; a < 4; ++a) {
        const int oh = oh0 + a;
        if (oh > 30) continue;             // uniform branch (oh0 wave-uniform)
        #pragma unroll
        for (int di = 0; di < 4; ++di) {
            const int r = oh - di;
            if (r < 0 || r >= 28) continue;
            #pragma unroll
            for (int k = 0; k < 11; ++k) {
                const int wp = wb - 3 + k;
                if (wp < 0 || wp >= 28) continue;
                const int l = r * 28 + wp;
                half4 v = *(const half4*)(patches + (size_t)l * (BS * D_TOT) + pboc + di * 4);
                #pragma unroll
                for (int dj = 0; dj < 4; ++dj) {
                    const int o = (k - 3) + dj;        // = wp + dj - wb, compile-time
                    if (o < 0 || o >= 8) continue;
                    if (wb + o <= 30)
                        acc[a][o] += (float)v[dj];
                }
            }
        }
    }

    #pragma unroll
    for (int a = 0; a < 4; ++a) {
        const int oh = oh0 + a;
        if (oh > 30) continue;
        float* op = out + (((size_t)b * OC_ + oc) * OH_ + oh) * OW_ + wb;
        #pragma unroll
        for (int o = 0; o < 8; ++o) {
            if (wb + o <= 30) op[o] = acc[a][o];
        }
    }
}

// ---------------------------------------------------------------------------
extern "C" void kernel_launch(void* const* d_in, const int* in_sizes, int n_in,
                              void* d_out, int out_size, void* d_ws, size_t ws_size,
                              hipStream_t stream) {
    const float* x = (const float*)d_in[0];
    const float* W = (const float*)d_in[1];
    float* out     = (float*)d_out;

    __hip_bfloat16* xp = (__hip_bfloat16*)d_ws;                       // 25.7 MB
    _Float16* patches  = (_Float16*)((char*)d_ws + 25690112);         // 102.8 MB

    pack_x<<<dim3(64, 8, 7), 256, 0, stream>>>(x, xp);
    lc_gemm<<<dim3(HW_ * 4), 256, 0, stream>>>(xp, W, patches);
    fold_k<<<dim3(64, 8), 256, 0, stream>>>(patches, out);
}

// Round 3
// 262.600 us; speedup vs baseline: 3.4219x; 1.0109x over previous
//
#include <hip/hip_runtime.h>
#include <hip/hip_bf16.h>

// Problem constants
#define HW_   784          // 28*28 locations
#define C_IN  256
#define BS    64
#define OC_   64
#define D_TOT 1024         // OC*4*4
#define OH_   31
#define OW_   31

typedef __attribute__((ext_vector_type(8))) short    short8;   // 8 bf16 (4 VGPR) MFMA A/B frag
typedef __attribute__((ext_vector_type(4))) float    f32x4;    // MFMA C/D frag
typedef __attribute__((ext_vector_type(4))) int      int4v;
typedef __attribute__((ext_vector_type(4))) float    fl4;
typedef __attribute__((ext_vector_type(4))) _Float16 half4;

static __device__ __forceinline__ short f2bf(float f) {
    // round-to-nearest-even fp32 -> bf16
    unsigned int u = __float_as_uint(f);
    unsigned int r = (u + 0x7fffu + ((u >> 16) & 1u)) >> 16;
    return (short)r;
}

// ---------------------------------------------------------------------------
// Kernel 0: pack x[b, c, l] (fp32, l contiguous) -> xp[l][b][c] (bf16, c contiguous)
// ---------------------------------------------------------------------------
__global__ __launch_bounds__(256) void pack_x(const float* __restrict__ x,
                                              __hip_bfloat16* __restrict__ xp) {
    const int b  = blockIdx.x;
    const int c0 = blockIdx.y * 32;
    const int l0 = blockIdx.z * 112;
    const int t  = threadIdx.x;

    __shared__ unsigned short tile[32][114];   // +2 pad -> conflict-free transpose reads

    for (int e = t; e < 32 * 112; e += 256) {
        int cl = e / 112, ll = e % 112;
        float v = x[(size_t)b * (C_IN * HW_) + (size_t)(c0 + cl) * HW_ + (l0 + ll)];
        tile[cl][ll] = (unsigned short)f2bf(v);
    }
    __syncthreads();

    for (int e = t; e < 112 * 32; e += 256) {
        int ll = e >> 5, cl = e & 31;
        xp[(size_t)(l0 + ll) * (BS * C_IN) + b * C_IN + (c0 + cl)] =
            *(const __hip_bfloat16*)&tile[cl][ll];
    }
}

// ---------------------------------------------------------------------------
// Kernel 1: per (location l, 256-wide d-chunk) GEMM  [64b x 256c] @ [256c x 256d]
// Weight streamed with coalesced dwordx4 -> in-reg k-transpose -> bf16 ->
// double-buffered LDS W^T [256 d][32 k] (XOR-swizzled). 2-phase pipeline:
// issue loads(t+1) / ds_read+MFMA(buf cur) / convert+ds_write(buf cur^1) / barrier.
// Writes patches[l][b][d] (fp16) via LDS transpose -> coalesced 16B stores.
// ---------------------------------------------------------------------------
__global__ __launch_bounds__(256) void lc_gemm(const __hip_bfloat16* __restrict__ xp,
                                               const float* __restrict__ W,
                                               _Float16* __restrict__ patches) {
    // XCD-aware swizzle: nwg = 3136 = 8 * 392; 4 chunks of one l stay on one XCD
    const int wg    = blockIdx.x;
    const int lcid  = (wg & 7) * 392 + (wg >> 3);
    const int l     = lcid >> 2;
    const int chunk = lcid & 3;

    const int t     = threadIdx.x;
    const int wave  = t >> 6;
    const int lane  = t & 63;
    const int g     = lane >> 4;      // 0..3  (k-group)
    const int ln    = lane & 15;      // row/col within fragment

    __shared__ __attribute__((aligned(16))) char lds[64 * 1024];
    char* alds = lds;                  // 32 KB: A tile [64 b][256 c] bf16, row = 512 B
    char* wlds = lds + 32 * 1024;      // 2 x 16 KB: W^T [256 d][32 k] bf16, row = 64 B

    // ---- stage A tile (coalesced 16B loads; XOR swizzle byte ^= (row&7)<<4) ----
    {
        const int4v* src = (const int4v*)(xp + (size_t)l * (BS * C_IN));
        #pragma unroll
        for (int it = 0; it < 8; ++it) {
            int ch  = t + it * 256;        // 16B granule id, 0..2047
            int row = ch >> 5;             // b row (512B per row)
            int col = ch & 31;             // 16B granule within row
            int4v v = src[ch];
            *(int4v*)(alds + row * 512 + ((col * 16) ^ ((row & 7) << 4))) = v;
        }
    }

    // ---- W staging setup: thread (kg = wave, dg = lane) owns k rows kg*8..+7,
    //      d cols dg*4..+3 of each 32k x 256d step tile ----
    const int kg = wave;
    const int dg = lane;
    const float* Wbase = W + (size_t)l * (C_IN * D_TOT) + chunk * 256 + dg * 4;
    const int wswz = (dg & 3) << 4;    // XOR swizzle for W^T rows

    fl4 wreg[8];

    // prologue: load step 0, convert+write buf0
    #pragma unroll
    for (int r = 0; r < 8; ++r)
        wreg[r] = *(const fl4*)(Wbase + (size_t)(kg * 8 + r) * D_TOT);
    #pragma unroll
    for (int j = 0; j < 4; ++j) {
        short8 pk;
        #pragma unroll
        for (int r = 0; r < 8; ++r) pk[r] = f2bf(wreg[r][j]);
        *(short8*)(wlds + (4 * dg + j) * 64 + ((kg * 16) ^ wswz)) = pk;
    }
    __syncthreads();   // A tile + W buf0 visible

    const int dbase = chunk * 256 + wave * 64;

    f32x4 acc[4][4];
    #pragma unroll
    for (int m = 0; m < 4; ++m)
        #pragma unroll
        for (int n = 0; n < 4; ++n)
            acc[m][n] = (f32x4){0.f, 0.f, 0.f, 0.f};

    for (int s = 0; s < 8; ++s) {
        char* wcur = wlds + (s & 1) * 16384;
        char* wnxt = wlds + ((s & 1) ^ 1) * 16384;
        const int k0 = s * 32;

        // issue next step's global loads (stay in flight across MFMA phase)
        if (s < 7) {
            #pragma unroll
            for (int r = 0; r < 8; ++r)
                wreg[r] = *(const fl4*)(Wbase + (size_t)(k0 + 32 + kg * 8 + r) * D_TOT);
        }

        // B fragments from W^T LDS: lane holds W[k0+g*8..+7][dbase+16n+ln]
        short8 bfr[4];
        #pragma unroll
        for (int n = 0; n < 4; ++n) {
            int dl = wave * 64 + 16 * n + ln;             // local d, 0..255
            bfr[n] = *(const short8*)(wcur + dl * 64 + ((g * 16) ^ ((ln >> 2) << 4)));
        }

        // A fragments from LDS: lane holds x[b = 16m + ln][k0 + g*8 .. +7]
        short8 af[4];
        #pragma unroll
        for (int m = 0; m < 4; ++m) {
            int row = 16 * m + ln;
            int off = row * 512 + ((((k0 + g * 8) << 1)) ^ ((row & 7) << 4));
            af[m] = *(const short8*)(alds + off);
        }

        #pragma unroll
        for (int m = 0; m < 4; ++m)
            #pragma unroll
            for (int n = 0; n < 4; ++n)
                acc[m][n] = __builtin_amdgcn_mfma_f32_16x16x32_bf16(af[m], bfr[n],
                                                                   acc[m][n], 0, 0, 0);

        // convert + write next buffer (waits on the global loads here)
        if (s < 7) {
            #pragma unroll
            for (int j = 0; j < 4; ++j) {
                short8 pk;
                #pragma unroll
                for (int r = 0; r < 8; ++r) pk[r] = f2bf(wreg[r][j]);
                *(short8*)(wnxt + (4 * dg + j) * 64 + ((kg * 16) ^ wswz)) = pk;
            }
        }
        __syncthreads();
    }

    // ---- epilogue: LDS transpose to fp16, then coalesced global stores ----
    _Float16* hl = (_Float16*)alds;        // reuse A region: [64 b][256 d'] fp16 = 32 KB
    #pragma unroll
    for (int m = 0; m < 4; ++m) {
        #pragma unroll
        for (int n = 0; n < 4; ++n) {
            #pragma unroll
            for (int r = 0; r < 4; ++r) {
                int b  = 16 * m + g * 4 + r;
                int dp = wave * 64 + 16 * n + ln;   // d' within this 256-chunk
                hl[b * 256 + dp] = (_Float16)acc[m][n][r];
            }
        }
    }
    __syncthreads();

    _Float16* dst = patches + (size_t)l * (BS * D_TOT) + chunk * 256;
    #pragma unroll
    for (int it = 0; it < 8; ++it) {
        int idx = t + it * 256;            // 16B granule id, 0..2047
        int row = idx >> 5;                // b (32 granules per 512B row)
        int gg  = idx & 31;
        *(int4v*)(dst + (size_t)row * D_TOT + gg * 8) =
            *(const int4v*)(hl + row * 256 + gg * 8);
    }
}

// ---------------------------------------------------------------------------
// Kernel 2: fold (overlap-add) gather — no atomics, every patch read once.
// Block = (b, oh-group of 4). Thread = (oc = t>>2, ww = t&3) owns ow = ww*8..+7.
// d encodes di -> each 8B piece (4 dj values) contributes to exactly one oh.
// ---------------------------------------------------------------------------
__global__ __launch_bounds__(256) void fold_k(const _Float16* __restrict__ patches,
                                              float* __restrict__ out) {
    const int b   = blockIdx.x;     // 0..63
    const int oh0 = blockIdx.y * 4; // 0,4,...,28
    const int t   = threadIdx.x;
    const int oc  = t >> 2;
    const int ww  = t & 3;
    const int wb  = ww * 8;

    float acc[4][8];
    #pragma unroll
    for (int a = 0; a < 4; ++a)
        #pragma unroll
        for (int o = 0; o < 8; ++o) acc[a][o] = 0.f;

    const size_t pboc = (size_t)b * D_TOT + (size_t)oc * 16;

    #pragma unroll
    for (int a = 0; a < 4; ++a) {
        const int oh = oh0 + a;
        if (oh > 30) continue;             // uniform branch (oh0 wave-uniform)
        #pragma unroll
        for (int di = 0; di < 4; ++di) {
            const int r = oh - di;
            if (r < 0 || r >= 28) continue;
            #pragma unroll
            for (int k = 0; k < 11; ++k) {
                const int wp = wb - 3 + k;
                if (wp < 0 || wp >= 28) continue;
                const int l = r * 28 + wp;
                half4 v = *(const half4*)(patches + (size_t)l * (BS * D_TOT) + pboc + di * 4);
                #pragma unroll
                for (int dj = 0; dj < 4; ++dj) {
                    const int o = (k - 3) + dj;        // = wp + dj - wb, compile-time
                    if (o < 0 || o >= 8) continue;
                    if (wb + o <= 30)
                        acc[a][o] += (float)v[dj];
                }
            }
        }
    }

    #pragma unroll
    for (int a = 0; a < 4; ++a) {
        const int oh = oh0 + a;
        if (oh > 30) continue;
        float* op = out + (((size_t)b * OC_ + oc) * OH_ + oh) * OW_ + wb;
        #pragma unroll
        for (int o = 0; o < 8; ++o) {
            if (wb + o <= 30) op[o] = acc[a][o];
        }
    }
}

// ---------------------------------------------------------------------------
extern "C" void kernel_launch(void* const* d_in, const int* in_sizes, int n_in,
                              void* d_out, int out_size, void* d_ws, size_t ws_size,
                              hipStream_t stream) {
    const float* x = (const float*)d_in[0];
    const float* W = (const float*)d_in[1];
    float* out     = (float*)d_out;

    __hip_bfloat16* xp = (__hip_bfloat16*)d_ws;                       // 25.7 MB
    _Float16* patches  = (_Float16*)((char*)d_ws + 25690112);         // 102.8 MB

    pack_x<<<dim3(64, 8, 7), 256, 0, stream>>>(x, xp);
    lc_gemm<<<dim3(HW_ * 4), 256, 0, stream>>>(xp, W, patches);
    fold_k<<<dim3(64, 8), 256, 0, stream>>>(patches, out);
}